// Round 5
// baseline (619.308 us; speedup 1.0000x reference)
//
#include <hip/hip_runtime.h>
#include <math.h>

static constexpr int NN = 200000;                 // nodes
static constexpr int NE = 6400000;                // edges (without self-loops)
static constexpr int TB = 256;
static constexpr int NBUCK = (NN + 255) / 256;    // 782 buckets of 256 nodes
static constexpr int CAP = 10240;                 // slots per bucket (mean 8192, +22 sigma)
static constexpr int CH = 16384;                  // edges per bin chunk
static constexpr int NCHUNK = (NE + CH - 1) / CH; // 391

// ---------------- CSR build ----------------

// bin edges into node-range buckets; payload = (src<<8) | dstLocal
// gcur[b] counts edges in bucket b (zeroed by memset; slot = b*CAP + reserved)
__global__ __launch_bounds__(TB) void k_bin(const int* __restrict__ src, const int* __restrict__ dst,
                                            int* __restrict__ gcur, int* __restrict__ csr) {
    __shared__ int hist[NBUCK];
    __shared__ int gbase[NBUCK];
    __shared__ int lcur[NBUCK];
    int t = threadIdx.x;
    int e0 = blockIdx.x * CH;
    int n = min(CH, NE - e0);
    for (int j = t; j < NBUCK; j += TB) { hist[j] = 0; lcur[j] = 0; }
    __syncthreads();
    for (int j = t; j < n; j += TB)
        atomicAdd(&hist[dst[e0 + j] >> 8], 1);
    __syncthreads();
    for (int j = t; j < NBUCK; j += TB) {
        int c = hist[j];
        gbase[j] = c ? atomicAdd(&gcur[j], c) : 0;   // one global atomic per (chunk,bucket)
    }
    __syncthreads();
    for (int j = t; j < n; j += TB) {
        int d = dst[e0 + j];                          // second read: L2-hot
        int s = __builtin_nontemporal_load(src + e0 + j);
        int b = d >> 8;
        int l = atomicAdd(&lcur[b], 1);               // LDS atomic
        int o = gbase[b] + l;
        if (o < CAP)                                  // overflow guard (astronomically rare)
            csr[b * CAP + o] = (s << 8) | (d & 255);
    }
}

__device__ __forceinline__ float mishf(float x) {
    float sp = (x > 20.f) ? x : log1pf(expf(x));
    return x * tanhf(sp);
}

// regroup each bucket by dstLocal fully in LDS; write back in place, coalesced.
// emits meta = (absStart<<8)|deg, dinv, and the fused layer-1 transform:
// planes (Ta|Tb)[node] = ((x[node] @ W1) * dinv) split 4+4
__global__ __launch_bounds__(TB) void k_group(const int* __restrict__ gcur, int* __restrict__ csr,
                                              unsigned* __restrict__ meta, float* __restrict__ dinv,
                                              const float* __restrict__ x, const float* __restrict__ W1,
                                              float4* __restrict__ Ta, float4* __restrict__ Tb) {
    __shared__ int hist[TB];
    __shared__ int scn[TB];
    __shared__ int cur[TB];
    __shared__ int grp[CAP];
    int t = threadIdx.x;
    int b = blockIdx.x;
    int base = b * CAP;
    int nE = min(gcur[b], CAP);
    hist[t] = 0; cur[t] = 0;
    __syncthreads();
    for (int j = t; j < nE; j += TB)
        atomicAdd(&hist[csr[base + j] & 255], 1);
    __syncthreads();
    int deg = hist[t];
    scn[t] = deg;
    __syncthreads();
#pragma unroll
    for (int o = 1; o < TB; o <<= 1) {
        int u = (t >= o) ? scn[t - o] : 0;
        __syncthreads();
        scn[t] += u;
        __syncthreads();
    }
    int off = scn[t] - deg;                          // exclusive
    int node = b * 256 + t;
    float di = rsqrtf((float)(deg + 1));
    if (node < NN) {
        meta[node] = ((unsigned)(base + off) << 8) | (unsigned)min(deg, 255);
        dinv[node] = di;
    }
    hist[t] = off;                                   // reuse as per-dl base
    __syncthreads();
    for (int j = t; j < nE; j += TB) {
        int p = csr[base + j];
        int dl = p & 255;
        int l = atomicAdd(&cur[dl], 1);
        grp[hist[dl] + l] = p >> 8;                  // src only
    }
    __syncthreads();
    for (int j = t; j < nE; j += TB) csr[base + j] = grp[j];

    // fused layer-1 transform (16 -> 8), pre-scaled by dinv, plane-split output
    if (node >= NN) return;
    float in[16];
    const float4* hp = (const float4*)(x + (size_t)node * 16);
#pragma unroll
    for (int q = 0; q < 4; ++q) {
        float4 v = hp[q];
        in[4*q+0] = v.x; in[4*q+1] = v.y; in[4*q+2] = v.z; in[4*q+3] = v.w;
    }
    float o[8];
#pragma unroll
    for (int f = 0; f < 8; ++f) o[f] = 0.f;
#pragma unroll
    for (int k = 0; k < 16; ++k)
#pragma unroll
        for (int f = 0; f < 8; ++f) o[f] = fmaf(in[k], W1[k * 8 + f], o[f]);
    Ta[node] = make_float4(o[0] * di, o[1] * di, o[2] * di, o[3] * di);
    Tb[node] = make_float4(o[4] * di, o[5] * di, o[6] * di, o[7] * di);
}

// ---------------- gather kernels (4 lanes per node) ----------------

// pass A: aggregate 4-dim plane (L2-resident) -> partial
__global__ __launch_bounds__(TB) void k_gA(const float4* __restrict__ plane,
                                           const unsigned* __restrict__ meta,
                                           const int* __restrict__ csr,
                                           float4* __restrict__ part) {
    int tid = blockIdx.x * TB + threadIdx.x;
    int node = tid >> 2;
    int lane = tid & 3;
    if (node >= NN) return;
    unsigned m = meta[node];
    int start = (int)(m >> 8);
    int deg = (int)(m & 255u);
    float a0 = 0.f, a1 = 0.f, a2 = 0.f, a3 = 0.f;
    if (lane == 0) {                                  // self-loop term
        float4 v = plane[node];
        a0 = v.x; a1 = v.y; a2 = v.z; a3 = v.w;
    }
#pragma unroll 2
    for (int e = lane; e < deg; e += 4) {
        int s = __builtin_nontemporal_load(csr + start + e);
        float4 v = plane[s];
        a0 += v.x; a1 += v.y; a2 += v.z; a3 += v.w;
    }
    a0 += __shfl_xor(a0, 1); a0 += __shfl_xor(a0, 2);
    a1 += __shfl_xor(a1, 1); a1 += __shfl_xor(a1, 2);
    a2 += __shfl_xor(a2, 1); a2 += __shfl_xor(a2, 2);
    a3 += __shfl_xor(a3, 1); a3 += __shfl_xor(a3, 2);
    if (lane == 0) part[node] = make_float4(a0, a1, a2, a3);
}

// pass B: aggregate other plane, combine with partial, post-process.
// MODE 1: out8 = mish(di*acc + b1)*di                     (P0=b1)           -> outA/outB
// MODE 2: h16 = mish((di*acc)@W2 + b2); out8=(h16@W3)*di  (P0=W2,P1=b2,P2=W3)-> outA/outB
// MODE 3: t8 = mish(di*acc + b3); out2=(t8@W4)*di         (P0=b3,P1=W4)     -> out2
template<int MODE>
__global__ __launch_bounds__(TB) void k_gB(const float4* __restrict__ plane,
                                           const unsigned* __restrict__ meta,
                                           const int* __restrict__ csr,
                                           const float4* __restrict__ part,
                                           const float* __restrict__ dinv,
                                           const float* __restrict__ P0, const float* __restrict__ P1,
                                           const float* __restrict__ P2,
                                           float4* __restrict__ outA, float4* __restrict__ outB,
                                           float2* __restrict__ out2) {
    int tid = blockIdx.x * TB + threadIdx.x;
    int node = tid >> 2;
    int lane = tid & 3;
    if (node >= NN) return;
    unsigned m = meta[node];
    int start = (int)(m >> 8);
    int deg = (int)(m & 255u);
    float a4 = 0.f, a5 = 0.f, a6 = 0.f, a7 = 0.f;
    if (lane == 0) {
        float4 v = plane[node];
        a4 = v.x; a5 = v.y; a6 = v.z; a7 = v.w;
    }
#pragma unroll 2
    for (int e = lane; e < deg; e += 4) {
        int s = __builtin_nontemporal_load(csr + start + e);
        float4 v = plane[s];
        a4 += v.x; a5 += v.y; a6 += v.z; a7 += v.w;
    }
    a4 += __shfl_xor(a4, 1); a4 += __shfl_xor(a4, 2);
    a5 += __shfl_xor(a5, 1); a5 += __shfl_xor(a5, 2);
    a6 += __shfl_xor(a6, 1); a6 += __shfl_xor(a6, 2);
    a7 += __shfl_xor(a7, 1); a7 += __shfl_xor(a7, 2);
    if (lane != 0) return;
    float4 p = part[node];
    float acc[8] = { p.x, p.y, p.z, p.w, a4, a5, a6, a7 };
    float di = dinv[node];
    if constexpr (MODE == 1) {
        float o[8];
#pragma unroll
        for (int f = 0; f < 8; ++f) o[f] = mishf(fmaf(acc[f], di, P0[f])) * di;
        outA[node] = make_float4(o[0], o[1], o[2], o[3]);
        outB[node] = make_float4(o[4], o[5], o[6], o[7]);
    } else if constexpr (MODE == 2) {
        float z[8];
#pragma unroll
        for (int f = 0; f < 8; ++f) z[f] = acc[f] * di;
        float h[16];
#pragma unroll
        for (int g = 0; g < 16; ++g) h[g] = P1[g];
#pragma unroll
        for (int f = 0; f < 8; ++f)
#pragma unroll
            for (int g = 0; g < 16; ++g) h[g] = fmaf(z[f], P0[f * 16 + g], h[g]);
#pragma unroll
        for (int g = 0; g < 16; ++g) h[g] = mishf(h[g]);
        float o[8];
#pragma unroll
        for (int q = 0; q < 8; ++q) o[q] = 0.f;
#pragma unroll
        for (int g = 0; g < 16; ++g)
#pragma unroll
            for (int q = 0; q < 8; ++q) o[q] = fmaf(h[g], P2[g * 8 + q], o[q]);
        outA[node] = make_float4(o[0] * di, o[1] * di, o[2] * di, o[3] * di);
        outB[node] = make_float4(o[4] * di, o[5] * di, o[6] * di, o[7] * di);
    } else {
        float t8[8];
#pragma unroll
        for (int f = 0; f < 8; ++f) t8[f] = mishf(fmaf(acc[f], di, P0[f]));
        float o0 = 0.f, o1 = 0.f;
#pragma unroll
        for (int f = 0; f < 8; ++f) {
            o0 = fmaf(t8[f], P1[f * 2 + 0], o0);
            o1 = fmaf(t8[f], P1[f * 2 + 1], o1);
        }
        out2[node] = make_float2(o0 * di, o1 * di);
    }
}

// final: 2-dim aggregation + bias + log_softmax (table 1.6 MB, L2-resident)
__global__ __launch_bounds__(TB) void k_g2(const float2* __restrict__ g, const unsigned* __restrict__ meta,
                                           const int* __restrict__ csr, const float* __restrict__ dinv,
                                           const float* __restrict__ b4, float* __restrict__ outp) {
    int tid = blockIdx.x * TB + threadIdx.x;
    int node = tid >> 2;
    int lane = tid & 3;
    if (node >= NN) return;
    unsigned m = meta[node];
    int start = (int)(m >> 8);
    int deg = (int)(m & 255u);
    float a0 = 0.f, a1 = 0.f;
    if (lane == 0) {
        float2 v = g[node];
        a0 = v.x; a1 = v.y;
    }
#pragma unroll 2
    for (int e = lane; e < deg; e += 4) {
        int s = __builtin_nontemporal_load(csr + start + e);
        float2 v = g[s];
        a0 += v.x; a1 += v.y;
    }
    a0 += __shfl_xor(a0, 1); a0 += __shfl_xor(a0, 2);
    a1 += __shfl_xor(a1, 1); a1 += __shfl_xor(a1, 2);
    if (lane != 0) return;
    float di = dinv[node];
    float z0 = fmaf(a0, di, b4[0]);
    float z1 = fmaf(a1, di, b4[1]);
    float mx = fmaxf(z0, z1);
    float l = mx + logf(expf(z0 - mx) + expf(z1 - mx));
    outp[(size_t)node * 2 + 0] = z0 - l;
    outp[(size_t)node * 2 + 1] = z1 - l;
}

// ---------------- launch ----------------

extern "C" void kernel_launch(void* const* d_in, const int* in_sizes, int n_in,
                              void* d_out, int out_size, void* d_ws, size_t ws_size,
                              hipStream_t stream) {
    const float* x   = (const float*)d_in[0];
    const int*   ei  = (const int*)d_in[1];       // [2, NE]
    const int*   src = ei;
    const int*   dst = ei + NE;
    const float* W1 = (const float*)d_in[2];
    const float* b1 = (const float*)d_in[3];
    const float* W2 = (const float*)d_in[4];
    const float* b2 = (const float*)d_in[5];
    const float* W3 = (const float*)d_in[6];
    const float* b3 = (const float*)d_in[7];
    const float* W4 = (const float*)d_in[8];
    const float* b4 = (const float*)d_in[9];
    float* out = (float*)d_out;

    char* ws = (char*)d_ws;
    size_t off_b = 0;
    auto alloc = [&](size_t bytes) -> void* {
        off_b = (off_b + 255) & ~(size_t)255;
        void* p = ws + off_b;
        off_b += bytes;
        return p;
    };
    int*      gcur = (int*)     alloc((size_t)NBUCK * 4);
    unsigned* meta = (unsigned*)alloc((size_t)NN * 4);
    float*    dinv = (float*)   alloc((size_t)NN * 4);
    int*      csr  = (int*)     alloc((size_t)NBUCK * CAP * 4);  // ~30.5 MB
    float4*   A0   = (float4*)  alloc((size_t)NN * 16);          // 3.2 MB plane
    float4*   A1   = (float4*)  alloc((size_t)NN * 16);
    float4*   B0   = (float4*)  alloc((size_t)NN * 16);
    float4*   B1   = (float4*)  alloc((size_t)NN * 16);
    float4*   part = (float4*)  alloc((size_t)NN * 16);
    float2*   T4   = (float2*)  alloc((size_t)NN * 8);
    (void)ws_size;

    const int gG = (NN * 4 + TB - 1) / TB;      // 4-lanes-per-node grids

    // CSR build + fused layer-1 transform
    hipMemsetAsync(gcur, 0, (size_t)NBUCK * 4, stream);
    k_bin<<<NCHUNK, TB, 0, stream>>>(src, dst, gcur, csr);
    k_group<<<NBUCK, TB, 0, stream>>>(gcur, csr, meta, dinv, x, W1, A0, A1);

    // layer 1: agg(T1) + b1 + mish -> T2
    k_gA<<<gG, TB, 0, stream>>>(A0, meta, csr, part);
    k_gB<1><<<gG, TB, 0, stream>>>(A1, meta, csr, part, dinv, b1, nullptr, nullptr, B0, B1, nullptr);

    // layer 2: agg(T2) @W2 + b2 + mish, @W3 -> T3
    k_gA<<<gG, TB, 0, stream>>>(B0, meta, csr, part);
    k_gB<2><<<gG, TB, 0, stream>>>(B1, meta, csr, part, dinv, W2, b2, W3, A0, A1, nullptr);

    // layer 3: agg(T3) + b3 + mish, @W4 -> T4
    k_gA<<<gG, TB, 0, stream>>>(A0, meta, csr, part);
    k_gB<3><<<gG, TB, 0, stream>>>(A1, meta, csr, part, dinv, b3, W4, nullptr, nullptr, nullptr, T4);

    // layer 4: agg(T4) + b4 + log_softmax
    k_g2<<<gG, TB, 0, stream>>>(T4, meta, csr, dinv, b4, out);
}

// Round 6
// 452.706 us; speedup vs baseline: 1.3680x; 1.3680x over previous
//
#include <hip/hip_runtime.h>
#include <math.h>

static constexpr int NN = 200000;                 // nodes
static constexpr int NE = 6400000;                // edges (without self-loops)
static constexpr int TB = 256;
static constexpr int NBUCK = (NN + 255) / 256;    // 782 buckets of 256 nodes
static constexpr int CAP = 10240;                 // slots per bucket (mean 8192, +22 sigma)
static constexpr int CH = 8192;                   // edges per bin chunk
static constexpr int NCHUNK = (NE + CH - 1) / CH; // 782

// ---------------- CSR build ----------------

// Bin edges into node-range buckets; payload = (src<<8) | dstLocal.
// Chunk is sorted by bucket in LDS first, then written out run-contiguous
// (consecutive lanes -> consecutive addresses) so HBM sees full-line bursts.
// gcur[b] = fill count of bucket b (zeroed by memset; csr slot = b*CAP + off).
__global__ __launch_bounds__(TB) void k_bin(const int* __restrict__ src, const int* __restrict__ dst,
                                            int* __restrict__ gcur, int* __restrict__ csr) {
    __shared__ int hist[NBUCK];            // per-bucket counts
    __shared__ int scn[NBUCK];             // inclusive scan -> cursor
    __shared__ int gb[NBUCK];              // b*CAP + gbase - excl  (dest = gb[b] + j)
    __shared__ int stage[CH];              // payloads sorted by bucket
    __shared__ unsigned short bkt[CH];     // bucket id per sorted slot
    int t = threadIdx.x;
    int e0 = blockIdx.x * CH;
    int n = min(CH, NE - e0);

    for (int j = t; j < NBUCK; j += TB) hist[j] = 0;
    __syncthreads();
    for (int j = t; j < n; j += TB)
        atomicAdd(&hist[dst[e0 + j] >> 8], 1);
    __syncthreads();
    for (int j = t; j < NBUCK; j += TB) scn[j] = hist[j];
    __syncthreads();
    // Hillis-Steele inclusive scan over NBUCK entries
    for (int off = 1; off < NBUCK; off <<= 1) {
        int v[4];
#pragma unroll
        for (int k = 0; k < 4; ++k) {
            int idx = t + k * TB;
            v[k] = (idx < NBUCK && idx >= off) ? scn[idx - off] : 0;
        }
        __syncthreads();
#pragma unroll
        for (int k = 0; k < 4; ++k) {
            int idx = t + k * TB;
            if (idx < NBUCK) scn[idx] += v[k];
        }
        __syncthreads();
    }
    // reserve global runs; convert scn to exclusive cursor; build dest delta
    for (int j = t; j < NBUCK; j += TB) {
        int c = hist[j];
        int excl = scn[j] - c;
        int gbase = c ? atomicAdd(&gcur[j], c) : 0;   // one global atomic per (chunk,bucket)
        gb[j] = j * CAP + gbase - excl;
        scn[j] = excl;                                // cursor starts at local excl
    }
    __syncthreads();
    // LDS scatter: bucket-sorted staging
    for (int j = t; j < n; j += TB) {
        int d = dst[e0 + j];                          // L2-hot second read
        int s = src[e0 + j];
        int b = d >> 8;
        int pos = atomicAdd(&scn[b], 1);
        stage[pos] = (s << 8) | (d & 255);
        bkt[pos] = (unsigned short)b;
    }
    __syncthreads();
    // run-contiguous write-out: consecutive j -> consecutive dest within runs
    for (int j = t; j < n; j += TB) {
        int b = bkt[j];
        int dest = gb[b] + j;
        if (dest < (b + 1) * CAP)                     // overflow guard (astronomically rare)
            csr[dest] = stage[j];
    }
}

__device__ __forceinline__ float mishf(float x) {
    float sp = (x > 20.f) ? x : log1pf(expf(x));
    return x * tanhf(sp);
}

// regroup each bucket by dstLocal fully in LDS; write back in place, coalesced.
// emits meta = (absStart<<8)|deg, dinv, and fused layer-1 transform:
// T1[node] = (x[node] @ W1) * dinv   (interleaved 8-float rows)
__global__ __launch_bounds__(TB) void k_group(const int* __restrict__ gcur, int* __restrict__ csr,
                                              unsigned* __restrict__ meta, float* __restrict__ dinv,
                                              const float* __restrict__ x, const float* __restrict__ W1,
                                              float* __restrict__ T1) {
    __shared__ int hist[TB];
    __shared__ int scn[TB];
    __shared__ int cur[TB];
    __shared__ int grp[CAP];
    int t = threadIdx.x;
    int b = blockIdx.x;
    int base = b * CAP;
    int nE = min(gcur[b], CAP);
    hist[t] = 0; cur[t] = 0;
    __syncthreads();
    for (int j = t; j < nE; j += TB)
        atomicAdd(&hist[csr[base + j] & 255], 1);
    __syncthreads();
    int deg = hist[t];
    scn[t] = deg;
    __syncthreads();
#pragma unroll
    for (int o = 1; o < TB; o <<= 1) {
        int u = (t >= o) ? scn[t - o] : 0;
        __syncthreads();
        scn[t] += u;
        __syncthreads();
    }
    int off = scn[t] - deg;                          // exclusive
    int node = b * 256 + t;
    float di = rsqrtf((float)(deg + 1));
    if (node < NN) {
        meta[node] = ((unsigned)(base + off) << 8) | (unsigned)min(deg, 255);
        dinv[node] = di;
    }
    hist[t] = off;                                   // reuse as per-dl base
    __syncthreads();
    for (int j = t; j < nE; j += TB) {
        int p = csr[base + j];
        int dl = p & 255;
        int l = atomicAdd(&cur[dl], 1);
        grp[hist[dl] + l] = p >> 8;                  // src only
    }
    __syncthreads();
    for (int j = t; j < nE; j += TB) csr[base + j] = grp[j];

    // fused layer-1 transform (16 -> 8), pre-scaled by dinv
    if (node >= NN) return;
    float in[16];
    const float4* hp = (const float4*)(x + (size_t)node * 16);
#pragma unroll
    for (int q = 0; q < 4; ++q) {
        float4 v = hp[q];
        in[4*q+0] = v.x; in[4*q+1] = v.y; in[4*q+2] = v.z; in[4*q+3] = v.w;
    }
    float o[8];
#pragma unroll
    for (int f = 0; f < 8; ++f) o[f] = 0.f;
#pragma unroll
    for (int k = 0; k < 16; ++k)
#pragma unroll
        for (int f = 0; f < 8; ++f) o[f] = fmaf(in[k], W1[k * 8 + f], o[f]);
    float* op = T1 + (size_t)node * 8;
#pragma unroll
    for (int f = 0; f < 8; ++f) op[f] = o[f] * di;
}

// ---------------- gather kernels (4 lanes per node) ----------------

// 8-dim aggregation + per-layer post-processing.
// MODE 1: out8 = mish(di*acc + b1)*di                      (P0=b1)
// MODE 2: h16 = mish((di*acc)@W2 + b2); out8 = (h16@W3)*di (P0=W2,P1=b2,P2=W3)
// MODE 3: t8 = mish(di*acc + b3); out2 = (t8@W4)*di        (P0=b3,P1=W4)
template<int MODE>
__global__ __launch_bounds__(TB) void k_gather8(const float* __restrict__ g, const unsigned* __restrict__ meta,
                                                const int* __restrict__ csr, const float* __restrict__ dinv,
                                                const float* __restrict__ P0, const float* __restrict__ P1,
                                                const float* __restrict__ P2, float* __restrict__ outp) {
    int tid = blockIdx.x * TB + threadIdx.x;
    int node = tid >> 2;
    int lane = tid & 3;
    if (node >= NN) return;
    unsigned m = meta[node];
    int start = (int)(m >> 8);
    int deg = (int)(m & 255u);
    float acc[8];
    if (lane == 0) {           // self-loop term
        const float4* sp = (const float4*)(g + (size_t)node * 8);
        float4 a = sp[0], b = sp[1];
        acc[0]=a.x; acc[1]=a.y; acc[2]=a.z; acc[3]=a.w;
        acc[4]=b.x; acc[5]=b.y; acc[6]=b.z; acc[7]=b.w;
    } else {
#pragma unroll
        for (int f = 0; f < 8; ++f) acc[f] = 0.f;
    }
    for (int e = lane; e < deg; e += 4) {
        int s = csr[start + e];
        const float4* sp = (const float4*)(g + (size_t)s * 8);
        float4 a = sp[0], b = sp[1];
        acc[0]+=a.x; acc[1]+=a.y; acc[2]+=a.z; acc[3]+=a.w;
        acc[4]+=b.x; acc[5]+=b.y; acc[6]+=b.z; acc[7]+=b.w;
    }
#pragma unroll
    for (int f = 0; f < 8; ++f) {
        acc[f] += __shfl_xor(acc[f], 1);
        acc[f] += __shfl_xor(acc[f], 2);
    }
    if (lane != 0) return;
    float di = dinv[node];
    if constexpr (MODE == 1) {
        float* op = outp + (size_t)node * 8;
#pragma unroll
        for (int f = 0; f < 8; ++f) op[f] = mishf(fmaf(acc[f], di, P0[f])) * di;
    } else if constexpr (MODE == 2) {
        float z[8];
#pragma unroll
        for (int f = 0; f < 8; ++f) z[f] = acc[f] * di;
        float h[16];
#pragma unroll
        for (int gg = 0; gg < 16; ++gg) h[gg] = P1[gg];
#pragma unroll
        for (int f = 0; f < 8; ++f)
#pragma unroll
            for (int gg = 0; gg < 16; ++gg) h[gg] = fmaf(z[f], P0[f * 16 + gg], h[gg]);
#pragma unroll
        for (int gg = 0; gg < 16; ++gg) h[gg] = mishf(h[gg]);
        float o[8];
#pragma unroll
        for (int q = 0; q < 8; ++q) o[q] = 0.f;
#pragma unroll
        for (int gg = 0; gg < 16; ++gg)
#pragma unroll
            for (int q = 0; q < 8; ++q) o[q] = fmaf(h[gg], P2[gg * 8 + q], o[q]);
        float* op = outp + (size_t)node * 8;
#pragma unroll
        for (int q = 0; q < 8; ++q) op[q] = o[q] * di;
    } else {  // MODE 3
        float t8[8];
#pragma unroll
        for (int f = 0; f < 8; ++f) t8[f] = mishf(fmaf(acc[f], di, P0[f]));
        float o0 = 0.f, o1 = 0.f;
#pragma unroll
        for (int f = 0; f < 8; ++f) {
            o0 = fmaf(t8[f], P1[f * 2 + 0], o0);
            o1 = fmaf(t8[f], P1[f * 2 + 1], o1);
        }
        float* op = outp + (size_t)node * 2;
        op[0] = o0 * di; op[1] = o1 * di;
    }
}

// final: 2-dim aggregation + bias + log_softmax
__global__ __launch_bounds__(TB) void k_gather2(const float* __restrict__ g, const unsigned* __restrict__ meta,
                                                const int* __restrict__ csr, const float* __restrict__ dinv,
                                                const float* __restrict__ b4, float* __restrict__ outp) {
    int tid = blockIdx.x * TB + threadIdx.x;
    int node = tid >> 2;
    int lane = tid & 3;
    if (node >= NN) return;
    unsigned m = meta[node];
    int start = (int)(m >> 8);
    int deg = (int)(m & 255u);
    float a0 = 0.f, a1 = 0.f;
    if (lane == 0) {
        float2 v = *(const float2*)(g + (size_t)node * 2);
        a0 = v.x; a1 = v.y;
    }
    for (int e = lane; e < deg; e += 4) {
        int s = csr[start + e];
        float2 v = *(const float2*)(g + (size_t)s * 2);
        a0 += v.x; a1 += v.y;
    }
    a0 += __shfl_xor(a0, 1); a0 += __shfl_xor(a0, 2);
    a1 += __shfl_xor(a1, 1); a1 += __shfl_xor(a1, 2);
    if (lane != 0) return;
    float di = dinv[node];
    float z0 = fmaf(a0, di, b4[0]);
    float z1 = fmaf(a1, di, b4[1]);
    float mx = fmaxf(z0, z1);
    float l = mx + logf(expf(z0 - mx) + expf(z1 - mx));
    outp[(size_t)node * 2 + 0] = z0 - l;
    outp[(size_t)node * 2 + 1] = z1 - l;
}

// ---------------- launch ----------------

extern "C" void kernel_launch(void* const* d_in, const int* in_sizes, int n_in,
                              void* d_out, int out_size, void* d_ws, size_t ws_size,
                              hipStream_t stream) {
    const float* x   = (const float*)d_in[0];
    const int*   ei  = (const int*)d_in[1];       // [2, NE]
    const int*   src = ei;
    const int*   dst = ei + NE;
    const float* W1 = (const float*)d_in[2];
    const float* b1 = (const float*)d_in[3];
    const float* W2 = (const float*)d_in[4];
    const float* b2 = (const float*)d_in[5];
    const float* W3 = (const float*)d_in[6];
    const float* b3 = (const float*)d_in[7];
    const float* W4 = (const float*)d_in[8];
    const float* b4 = (const float*)d_in[9];
    float* out = (float*)d_out;

    char* ws = (char*)d_ws;
    size_t off_b = 0;
    auto alloc = [&](size_t bytes) -> void* {
        off_b = (off_b + 255) & ~(size_t)255;
        void* p = ws + off_b;
        off_b += bytes;
        return p;
    };
    int*      gcur = (int*)     alloc((size_t)NBUCK * 4);
    unsigned* meta = (unsigned*)alloc((size_t)NN * 4);
    float*    dinv = (float*)   alloc((size_t)NN * 4);
    int*      csr  = (int*)     alloc((size_t)NBUCK * CAP * 4);  // ~30.5 MB
    float*    TA   = (float*)   alloc((size_t)NN * 8 * 4);       // 6.4 MB
    float*    TBuf = (float*)   alloc((size_t)NN * 8 * 4);       // 6.4 MB
    float*    T2f  = (float*)   alloc((size_t)NN * 2 * 4);       // 1.6 MB
    (void)ws_size;

    const int gG = (NN * 4 + TB - 1) / TB;      // 4-lanes-per-node grids

    // CSR build + fused layer-1 transform
    hipMemsetAsync(gcur, 0, (size_t)NBUCK * 4, stream);
    k_bin<<<NCHUNK, TB, 0, stream>>>(src, dst, gcur, csr);
    k_group<<<NBUCK, TB, 0, stream>>>(gcur, csr, meta, dinv, x, W1, TA);

    // layer chain: all aggregations 8-dim (last 2-dim)
    k_gather8<1><<<gG, TB, 0, stream>>>(TA, meta, csr, dinv, b1, nullptr, nullptr, TBuf);   // L1 -> T2
    k_gather8<2><<<gG, TB, 0, stream>>>(TBuf, meta, csr, dinv, W2, b2, W3, TA);             // L2 -> T3
    k_gather8<3><<<gG, TB, 0, stream>>>(TA, meta, csr, dinv, b3, W4, nullptr, T2f);         // L3 -> T4
    k_gather2<<<gG, TB, 0, stream>>>(T2f, meta, csr, dinv, b4, out);                        // L4 + lsm
}

// Round 7
// 384.034 us; speedup vs baseline: 1.6126x; 1.1788x over previous
//
#include <hip/hip_runtime.h>
#include <hip/hip_fp16.h>
#include <math.h>

static constexpr int NN = 200000;                 // nodes
static constexpr int NE = 6400000;                // edges (without self-loops)
static constexpr int TB = 256;
static constexpr int NBUCK = (NN + 255) / 256;    // 782 buckets of 256 nodes
static constexpr int CAP = 10240;                 // slots per bucket (mean 8192, +22 sigma)
static constexpr int CH = 8192;                   // edges per bin chunk
static constexpr int NCHUNK = (NE + CH - 1) / CH; // 782

// ---------------- fp16 helpers ----------------

__device__ __forceinline__ float2 h2f(int b) {
    union { int i; __half2 h; } u; u.i = b;
    return __half22float2(u.h);
}
__device__ __forceinline__ int f2h(float a, float b) {
    union { __half2 h; int i; } u; u.h = __floats2half2_rn(a, b);
    return u.i;
}
__device__ __forceinline__ void acc8(const int4 r, float* acc) {
    float2 f;
    f = h2f(r.x); acc[0] += f.x; acc[1] += f.y;
    f = h2f(r.y); acc[2] += f.x; acc[3] += f.y;
    f = h2f(r.z); acc[4] += f.x; acc[5] += f.y;
    f = h2f(r.w); acc[6] += f.x; acc[7] += f.y;
}
__device__ __forceinline__ int4 pack8(const float* o) {
    int4 r;
    r.x = f2h(o[0], o[1]); r.y = f2h(o[2], o[3]);
    r.z = f2h(o[4], o[5]); r.w = f2h(o[6], o[7]);
    return r;
}

__device__ __forceinline__ float mishf(float x) {
    float sp = (x > 20.f) ? x : log1pf(expf(x));
    return x * tanhf(sp);
}

// ---------------- CSR build ----------------

// Bin edges into node-range buckets; payload = (src<<8) | dstLocal.
// Chunk sorted by bucket in LDS, written out run-contiguous.
__global__ __launch_bounds__(TB) void k_bin(const int* __restrict__ src, const int* __restrict__ dst,
                                            int* __restrict__ gcur, int* __restrict__ csr) {
    __shared__ int hist[NBUCK];
    __shared__ int scn[NBUCK];
    __shared__ int gb[NBUCK];
    __shared__ int stage[CH];
    __shared__ unsigned short bkt[CH];
    int t = threadIdx.x;
    int e0 = blockIdx.x * CH;
    int n = min(CH, NE - e0);

    for (int j = t; j < NBUCK; j += TB) hist[j] = 0;
    __syncthreads();
    for (int j = t; j < n; j += TB)
        atomicAdd(&hist[dst[e0 + j] >> 8], 1);
    __syncthreads();
    for (int j = t; j < NBUCK; j += TB) scn[j] = hist[j];
    __syncthreads();
    for (int off = 1; off < NBUCK; off <<= 1) {
        int v[4];
#pragma unroll
        for (int k = 0; k < 4; ++k) {
            int idx = t + k * TB;
            v[k] = (idx < NBUCK && idx >= off) ? scn[idx - off] : 0;
        }
        __syncthreads();
#pragma unroll
        for (int k = 0; k < 4; ++k) {
            int idx = t + k * TB;
            if (idx < NBUCK) scn[idx] += v[k];
        }
        __syncthreads();
    }
    for (int j = t; j < NBUCK; j += TB) {
        int c = hist[j];
        int excl = scn[j] - c;
        int gbase = c ? atomicAdd(&gcur[j], c) : 0;
        gb[j] = j * CAP + gbase - excl;
        scn[j] = excl;
    }
    __syncthreads();
    for (int j = t; j < n; j += TB) {
        int d = dst[e0 + j];
        int s = src[e0 + j];
        int b = d >> 8;
        int pos = atomicAdd(&scn[b], 1);
        stage[pos] = (s << 8) | (d & 255);
        bkt[pos] = (unsigned short)b;
    }
    __syncthreads();
    for (int j = t; j < n; j += TB) {
        int b = bkt[j];
        int dest = gb[b] + j;
        if (dest < (b + 1) * CAP)
            csr[dest] = stage[j];
    }
}

// regroup bucket by dstLocal in LDS; emits meta, dinv, degree-histogram,
// and fused layer-1 transform T1[node] = fp16((x @ W1) * dinv)
__global__ __launch_bounds__(TB) void k_group(const int* __restrict__ gcur, int* __restrict__ csr,
                                              unsigned* __restrict__ meta, float* __restrict__ dinv,
                                              int* __restrict__ dh,
                                              const float* __restrict__ x, const float* __restrict__ W1,
                                              int4* __restrict__ T1) {
    __shared__ int hist[TB];
    __shared__ int scn[TB];
    __shared__ int cur[TB];
    __shared__ int grp[CAP];
    int t = threadIdx.x;
    int b = blockIdx.x;
    int base = b * CAP;
    int nE = min(gcur[b], CAP);
    hist[t] = 0; cur[t] = 0;
    __syncthreads();
    for (int j = t; j < nE; j += TB)
        atomicAdd(&hist[csr[base + j] & 255], 1);
    __syncthreads();
    int deg = hist[t];
    scn[t] = deg;
    __syncthreads();
#pragma unroll
    for (int o = 1; o < TB; o <<= 1) {
        int u = (t >= o) ? scn[t - o] : 0;
        __syncthreads();
        scn[t] += u;
        __syncthreads();
    }
    int off = scn[t] - deg;
    int node = b * 256 + t;
    int degc = min(deg, 255);
    float di = rsqrtf((float)(deg + 1));
    if (node < NN) {
        meta[node] = ((unsigned)(base + off) << 8) | (unsigned)degc;
        dinv[node] = di;
    }
    hist[t] = off;
    __syncthreads();
    for (int j = t; j < nE; j += TB) {
        int p = csr[base + j];
        int dl = p & 255;
        int l = atomicAdd(&cur[dl], 1);
        grp[hist[dl] + l] = p >> 8;
    }
    __syncthreads();
    for (int j = t; j < nE; j += TB) csr[base + j] = grp[j];

    // degree histogram (LDS-aggregated)
    __syncthreads();
    cur[t] = 0;
    __syncthreads();
    if (node < NN) atomicAdd(&cur[degc], 1);
    __syncthreads();
    if (cur[t]) atomicAdd(&dh[t], cur[t]);

    // fused layer-1 transform (16 -> 8), pre-scaled by dinv, fp16 output
    if (node >= NN) return;
    float in[16];
    const float4* hp = (const float4*)(x + (size_t)node * 16);
#pragma unroll
    for (int q = 0; q < 4; ++q) {
        float4 v = hp[q];
        in[4*q+0] = v.x; in[4*q+1] = v.y; in[4*q+2] = v.z; in[4*q+3] = v.w;
    }
    float o[8];
#pragma unroll
    for (int f = 0; f < 8; ++f) o[f] = 0.f;
#pragma unroll
    for (int k = 0; k < 16; ++k)
#pragma unroll
        for (int f = 0; f < 8; ++f) o[f] = fmaf(in[k], W1[k * 8 + f], o[f]);
#pragma unroll
    for (int f = 0; f < 8; ++f) o[f] *= di;
    T1[node] = pack8(o);
}

// ---------------- degree-sort permutation ----------------

__global__ void k_dscan(const int* __restrict__ dh, int* __restrict__ dcur) {
    __shared__ int sm[256];
    int t = threadIdx.x;
    int v = dh[t];
    sm[t] = v;
    __syncthreads();
    for (int o = 1; o < 256; o <<= 1) {
        int u = (t >= o) ? sm[t - o] : 0;
        __syncthreads();
        sm[t] += u;
        __syncthreads();
    }
    dcur[t] = sm[t] - v;   // exclusive
}

__global__ __launch_bounds__(TB) void k_dperm(const unsigned* __restrict__ meta, int* __restrict__ dcur,
                                              int* __restrict__ perm) {
    __shared__ int lh[256];
    __shared__ int lbase[256];
    __shared__ int lcur[256];
    int t = threadIdx.x;
    int node = blockIdx.x * TB + t;
    lh[t] = 0; lcur[t] = 0;
    __syncthreads();
    int deg = 0;
    if (node < NN) {
        deg = (int)(meta[node] & 255u);
        atomicAdd(&lh[deg], 1);
    }
    __syncthreads();
    int c = lh[t];
    lbase[t] = c ? atomicAdd(&dcur[t], c) : 0;
    __syncthreads();
    if (node < NN) {
        int slot = lbase[deg] + atomicAdd(&lcur[deg], 1);
        perm[slot] = node;
    }
}

// ---------------- gather kernels (4 lanes per node, degree-sorted) ----------------

// 8-dim fp16 aggregation + per-layer post-processing.
// MODE 1: outH = fp16(mish(di*acc + b1)*di)                  (P0=b1)
// MODE 2: h16 = mish((di*acc)@W2 + b2); outH=fp16((h16@W3)*di)(P0=W2,P1=b2,P2=W3)
// MODE 3: t8 = mish(di*acc + b3); out2=(t8@W4)*di            (P0=b3,P1=W4)
template<int MODE>
__global__ __launch_bounds__(TB) void k_gather8(const int4* __restrict__ tab, const int* __restrict__ perm,
                                                const unsigned* __restrict__ meta,
                                                const int* __restrict__ csr, const float* __restrict__ dinv,
                                                const float* __restrict__ P0, const float* __restrict__ P1,
                                                const float* __restrict__ P2,
                                                int4* __restrict__ outH, float2* __restrict__ out2) {
    int tid = blockIdx.x * TB + threadIdx.x;
    int pid = tid >> 2;
    int lane = tid & 3;
    if (pid >= NN) return;
    int node = perm[pid];
    unsigned m = meta[node];
    int start = (int)(m >> 8);
    int deg = (int)(m & 255u);
    float acc[8];
#pragma unroll
    for (int f = 0; f < 8; ++f) acc[f] = 0.f;
    if (lane == 0) acc8(tab[node], acc);   // self-loop term
    int e = lane;
    for (; e + 12 < deg; e += 16) {        // quad: 4 independent load chains
        int s0 = csr[start + e];
        int s1 = csr[start + e + 4];
        int s2 = csr[start + e + 8];
        int s3 = csr[start + e + 12];
        int4 r0 = tab[s0];
        int4 r1 = tab[s1];
        int4 r2 = tab[s2];
        int4 r3 = tab[s3];
        acc8(r0, acc); acc8(r1, acc); acc8(r2, acc); acc8(r3, acc);
    }
    for (; e + 4 < deg; e += 8) {          // pair
        int s0 = csr[start + e];
        int s1 = csr[start + e + 4];
        int4 r0 = tab[s0];
        int4 r1 = tab[s1];
        acc8(r0, acc); acc8(r1, acc);
    }
    for (; e < deg; e += 4) {              // single
        acc8(tab[csr[start + e]], acc);
    }
#pragma unroll
    for (int f = 0; f < 8; ++f) {
        acc[f] += __shfl_xor(acc[f], 1);
        acc[f] += __shfl_xor(acc[f], 2);
    }
    if (lane != 0) return;
    float di = dinv[node];
    if constexpr (MODE == 1) {
        float o[8];
#pragma unroll
        for (int f = 0; f < 8; ++f) o[f] = mishf(fmaf(acc[f], di, P0[f])) * di;
        outH[node] = pack8(o);
    } else if constexpr (MODE == 2) {
        float z[8];
#pragma unroll
        for (int f = 0; f < 8; ++f) z[f] = acc[f] * di;
        float h[16];
#pragma unroll
        for (int g = 0; g < 16; ++g) h[g] = P1[g];
#pragma unroll
        for (int f = 0; f < 8; ++f)
#pragma unroll
            for (int g = 0; g < 16; ++g) h[g] = fmaf(z[f], P0[f * 16 + g], h[g]);
#pragma unroll
        for (int g = 0; g < 16; ++g) h[g] = mishf(h[g]);
        float o[8];
#pragma unroll
        for (int q = 0; q < 8; ++q) o[q] = 0.f;
#pragma unroll
        for (int g = 0; g < 16; ++g)
#pragma unroll
            for (int q = 0; q < 8; ++q) o[q] = fmaf(h[g], P2[g * 8 + q], o[q]);
#pragma unroll
        for (int q = 0; q < 8; ++q) o[q] *= di;
        outH[node] = pack8(o);
    } else {  // MODE 3
        float t8[8];
#pragma unroll
        for (int f = 0; f < 8; ++f) t8[f] = mishf(fmaf(acc[f], di, P0[f]));
        float o0 = 0.f, o1 = 0.f;
#pragma unroll
        for (int f = 0; f < 8; ++f) {
            o0 = fmaf(t8[f], P1[f * 2 + 0], o0);
            o1 = fmaf(t8[f], P1[f * 2 + 1], o1);
        }
        out2[node] = make_float2(o0 * di, o1 * di);
    }
}

// final: 2-dim fp32 aggregation + bias + log_softmax
__global__ __launch_bounds__(TB) void k_gather2(const float2* __restrict__ g, const int* __restrict__ perm,
                                                const unsigned* __restrict__ meta,
                                                const int* __restrict__ csr, const float* __restrict__ dinv,
                                                const float* __restrict__ b4, float* __restrict__ outp) {
    int tid = blockIdx.x * TB + threadIdx.x;
    int pid = tid >> 2;
    int lane = tid & 3;
    if (pid >= NN) return;
    int node = perm[pid];
    unsigned m = meta[node];
    int start = (int)(m >> 8);
    int deg = (int)(m & 255u);
    float a0 = 0.f, a1 = 0.f;
    if (lane == 0) {
        float2 v = g[node];
        a0 = v.x; a1 = v.y;
    }
    int e = lane;
    for (; e + 4 < deg; e += 8) {
        int s0 = csr[start + e];
        int s1 = csr[start + e + 4];
        float2 v0 = g[s0];
        float2 v1 = g[s1];
        a0 += v0.x + v1.x; a1 += v0.y + v1.y;
    }
    for (; e < deg; e += 4) {
        float2 v = g[csr[start + e]];
        a0 += v.x; a1 += v.y;
    }
    a0 += __shfl_xor(a0, 1); a0 += __shfl_xor(a0, 2);
    a1 += __shfl_xor(a1, 1); a1 += __shfl_xor(a1, 2);
    if (lane != 0) return;
    float di = dinv[node];
    float z0 = fmaf(a0, di, b4[0]);
    float z1 = fmaf(a1, di, b4[1]);
    float mx = fmaxf(z0, z1);
    float l = mx + logf(expf(z0 - mx) + expf(z1 - mx));
    outp[(size_t)node * 2 + 0] = z0 - l;
    outp[(size_t)node * 2 + 1] = z1 - l;
}

// ---------------- launch ----------------

extern "C" void kernel_launch(void* const* d_in, const int* in_sizes, int n_in,
                              void* d_out, int out_size, void* d_ws, size_t ws_size,
                              hipStream_t stream) {
    const float* x   = (const float*)d_in[0];
    const int*   ei  = (const int*)d_in[1];       // [2, NE]
    const int*   src = ei;
    const int*   dst = ei + NE;
    const float* W1 = (const float*)d_in[2];
    const float* b1 = (const float*)d_in[3];
    const float* W2 = (const float*)d_in[4];
    const float* b2 = (const float*)d_in[5];
    const float* W3 = (const float*)d_in[6];
    const float* b3 = (const float*)d_in[7];
    const float* W4 = (const float*)d_in[8];
    const float* b4 = (const float*)d_in[9];
    float* out = (float*)d_out;

    char* ws = (char*)d_ws;
    size_t off_b = 0;
    auto alloc = [&](size_t bytes) -> void* {
        off_b = (off_b + 255) & ~(size_t)255;
        void* p = ws + off_b;
        off_b += bytes;
        return p;
    };
    int*      gcur = (int*)     alloc((size_t)NBUCK * 4);
    int*      dh   = (int*)     alloc(256 * 4);
    int*      dcur = (int*)     alloc(256 * 4);
    unsigned* meta = (unsigned*)alloc((size_t)NN * 4);
    float*    dinv = (float*)   alloc((size_t)NN * 4);
    int*      perm = (int*)     alloc((size_t)NN * 4);
    int*      csr  = (int*)     alloc((size_t)NBUCK * CAP * 4);  // ~30.5 MB
    int4*     HA   = (int4*)    alloc((size_t)NN * 16);          // fp16 tables, 3.2 MB
    int4*     HB   = (int4*)    alloc((size_t)NN * 16);
    float2*   T4   = (float2*)  alloc((size_t)NN * 8);
    (void)ws_size;

    const int gG = (NN * 4 + TB - 1) / TB;      // 4-lanes-per-node grids
    const int gP = (NN + TB - 1) / TB;

    // CSR build + fused layer-1 transform + degree histogram
    hipMemsetAsync(gcur, 0, (size_t)NBUCK * 4, stream);
    hipMemsetAsync(dh, 0, 256 * 4, stream);
    k_bin<<<NCHUNK, TB, 0, stream>>>(src, dst, gcur, csr);
    k_group<<<NBUCK, TB, 0, stream>>>(gcur, csr, meta, dinv, dh, x, W1, HA);

    // degree-sorted permutation
    k_dscan<<<1, 256, 0, stream>>>(dh, dcur);
    k_dperm<<<gP, TB, 0, stream>>>(meta, dcur, perm);

    // layer chain (fp16 tables, fp32 accumulation)
    k_gather8<1><<<gG, TB, 0, stream>>>(HA, perm, meta, csr, dinv, b1, nullptr, nullptr, HB, nullptr); // L1
    k_gather8<2><<<gG, TB, 0, stream>>>(HB, perm, meta, csr, dinv, W2, b2, W3, HA, nullptr);           // L2
    k_gather8<3><<<gG, TB, 0, stream>>>(HA, perm, meta, csr, dinv, b3, W4, nullptr, nullptr, T4);      // L3
    k_gather2<<<gG, TB, 0, stream>>>(T4, perm, meta, csr, dinv, b4, out);                              // L4
}